// Round 1
// 194.115 us; speedup vs baseline: 1.0976x; 1.0976x over previous
//
#include <hip/hip_runtime.h>
#include <hip/hip_bf16.h>

#define N_NODES 50000
#define N_EDGES 800000
#define BM 64
#define NBUCK 196            // buckets of 256 nodes: d >> 8
#define CAP 6144             // fixed capacity per bucket (mean 4081, >30 sigma)
#define CHUNK 2048           // edges per block in bucket pass (391 blocks)
#define NB_BUCKET_BLOCKS ((N_EDGES + CHUNK - 1) / CHUNK)   // 391
#define SWZ_BLOCKS 192                                     // 49152 halves
#define SWZ_G 32768          // W_gat offset in swz
#define BFT 1024             // k_bfill threads

typedef _Float16 half4v __attribute__((ext_vector_type(4)));
typedef _Float16 half8 __attribute__((ext_vector_type(8)));
typedef float    float4v __attribute__((ext_vector_type(4)));

__device__ __forceinline__ float elu_f(float v) {
    return (v > 0.f) ? v : (__expf(v) - 1.f);
}

// pack two fp32 -> packed bf16x2 (RNE)
__device__ __forceinline__ unsigned f2bf2(float a, float b) {
    unsigned ua = __float_as_uint(a), ub = __float_as_uint(b);
    ua = (ua + 0x7FFFu + ((ua >> 16) & 1u)) >> 16;
    ub = (ub + 0x7FFFu + ((ub >> 16) & 1u)) >> 16;
    return ua | (ub << 16);
}
__device__ __forceinline__ float2 bf2f2(unsigned u) {
    float2 f;
    f.x = __uint_as_float(u << 16);
    f.y = __uint_as_float(u & 0xFFFF0000u);
    return f;
}

// ---------------- pre-pass: weight swizzle + {detect, bcursor zero} ------
// swz layout: [We 0..8192) N=64 | [Wd 8192..16384) N=128 | [Wo 16384..32768)
// N=128 | [Wg 32768..49152) N=128.  B-frag: frag=kc*nnt+nt, within frag
// lane holds B[k=kc*32+(lane>>4)*8+j][n=nt*16+(lane&15)], j=0..7.
__global__ __launch_bounds__(256) void k_pre(const void* __restrict__ e_raw,
        int* __restrict__ flag,
        const float* __restrict__ We, const float* __restrict__ Wd,
        const float* __restrict__ Wo, const float* __restrict__ Wg,
        _Float16* __restrict__ swz, int* __restrict__ bcursor) {
    const int b = blockIdx.x;
    const int tid = threadIdx.x;
    if (b >= SWZ_BLOCKS) {
        // edge dtype detect (high words all zero over 2048 samples => int64)
        __shared__ int nz;
        if (tid == 0) nz = 0;
        bcursor[tid] = 0;
        __syncthreads();
        int cnt = 0;
        const unsigned* er = (const unsigned*)e_raw;
        for (int i = tid; i < 2048; i += 256)
            if (er[2 * i + 1] != 0u) cnt = 1;
        if (cnt) atomicOr(&nz, 1);
        __syncthreads();
        if (tid == 0) *flag = (nz == 0) ? 1 : 0;   // 1 == int64 layout
        return;
    }
    int t = b * 256 + tid;
    const float* W; int base, N;
    if (t < 8192)       { W = We; base = 0;     N = 64;  }
    else if (t < 16384) { W = Wd; base = 8192;  N = 128; }
    else if (t < 32768) { W = Wo; base = 16384; N = 128; }
    else                { W = Wg; base = SWZ_G; N = 128; }
    int loc = t - base;
    int nnt = N >> 4;
    int frag = loc >> 9, r = loc & 511, lane = r >> 3, j = r & 7;
    int kc = frag / nnt, nt = frag - kc * nnt;
    int k = kc * 32 + ((lane >> 4) << 3) + j;
    int n = nt * 16 + (lane & 15);
    swz[t] = (_Float16)W[k * N + n];
}

// ---------------- K1: h(bf16) = x @ W_gat via MFMA; att head dots --------
// 64 rows/block, 4 waves, wave slab = 16 rows. K=128, N=128.
__global__ __launch_bounds__(256) void k_gat_lin(const float* __restrict__ x,
        const _Float16* __restrict__ swz, const float* __restrict__ att_s,
        const float* __restrict__ att_d, unsigned* __restrict__ h_bf,
        float* __restrict__ a_src, float* __restrict__ a_dst) {
    __shared__ _Float16 sx[64 * 128];   // 16 KB  x-tile f16
    __shared__ float sh[64 * 132];      // 33.8 KB h-tile f32 (pad 132: 2-way free)
    const int tid = threadIdx.x;
    const int m0 = blockIdx.x * 64;

    // stage x -> f16 LDS
#pragma unroll
    for (int i = 0; i < 8; i++) {
        int idx = tid + i * 256;        // 2048 float4 slots (64 x 32)
        int r = idx >> 5, c4 = idx & 31;
        int row = m0 + r; if (row >= N_NODES) row = N_NODES - 1;
        float4 v = ((const float4*)(x + (size_t)row * 128))[c4];
        half4v h;
        h[0] = (_Float16)v.x; h[1] = (_Float16)v.y;
        h[2] = (_Float16)v.z; h[3] = (_Float16)v.w;
        *(half4v*)&sx[r * 128 + c4 * 4] = h;
    }
    __syncthreads();

    const int wave = tid >> 6, lane = tid & 63;
    const int lm = lane & 15, lq = lane >> 4;
    const int wrow = wave * 16;

    {
        float4v acc[8];
#pragma unroll
        for (int nt = 0; nt < 8; nt++) acc[nt] = (float4v){0.f, 0.f, 0.f, 0.f};
#pragma unroll
        for (int kc = 0; kc < 4; kc++) {
            half8 a = *(const half8*)&sx[(wrow + lm) * 128 + kc * 32 + lq * 8];
#pragma unroll
            for (int nt = 0; nt < 8; nt++) {
                half8 b = *(const half8*)&swz[SWZ_G + (kc * 8 + nt) * 512 + lane * 8];
                acc[nt] = __builtin_amdgcn_mfma_f32_16x16x32_f16(a, b, acc[nt], 0, 0, 0);
            }
        }
        // C/D layout: col = nt*16 + lm, row = lq*4 + r
#pragma unroll
        for (int nt = 0; nt < 8; nt++)
#pragma unroll
            for (int r = 0; r < 4; r++)
                sh[(wrow + lq * 4 + r) * 132 + nt * 16 + lm] = acc[nt][r];
    }
    __syncthreads();

    // epilogue: pack bf16 h + attention dots (8 rows x 4 cols per thread)
    const int c0 = (tid & 31) * 4;
    const int r0 = (tid >> 5) * 8;
    float4 as4 = *(const float4*)&att_s[c0];
    float4 ad4 = *(const float4*)&att_d[c0];
    const int head = c0 >> 5;

#pragma unroll
    for (int r = 0; r < 8; r++) {
        int row = m0 + r0 + r;
        bool ok = row < N_NODES;
        float4 hv = *(const float4*)&sh[(r0 + r) * 132 + c0];
        if (ok) {
            uint2 p;
            p.x = f2bf2(hv.x, hv.y);
            p.y = f2bf2(hv.z, hv.w);
            *(uint2*)&h_bf[(size_t)row * 64 + (c0 >> 1)] = p;
        }
        float vs = hv.x * as4.x + hv.y * as4.y + hv.z * as4.z + hv.w * as4.w;
        float vd = hv.x * ad4.x + hv.y * ad4.y + hv.z * ad4.z + hv.w * ad4.w;
#pragma unroll
        for (int o = 4; o >= 1; o >>= 1) {
            vs += __shfl_down(vs, o, 8);
            vd += __shfl_down(vd, o, 8);
        }
        if (ok && (tid & 7) == 0) {
            a_src[row * 4 + head] = vs;
            a_dst[row * 4 + head] = vd;
        }
    }
}

// ---------------- CSR build: single-pass fixed-cap bucket sort -----------
// reads the RAW edge buffer (int64 or int32 per *flag) — no repack pass.
__global__ __launch_bounds__(256) void k_bucket(const void* __restrict__ e_raw,
        const int* __restrict__ flag, int* __restrict__ bcursor,
        uint2* __restrict__ ebuck) {
    __shared__ int lh[256];
    __shared__ int gbase[256];
    __shared__ int lcur[256];
    const int tid = threadIdx.x;
    const int base = blockIdx.x * CHUNK;
    const int is64 = *flag;
    const long long* e64 = (const long long*)e_raw;
    const int* e32 = (const int*)e_raw;

    lh[tid] = 0;
    __syncthreads();
#pragma unroll 4
    for (int j = 0; j < CHUNK / 256; j++) {
        int e = base + j * 256 + tid;
        if (e < N_EDGES) {
            int d = is64 ? (int)e64[N_EDGES + e] : e32[N_EDGES + e];
            atomicAdd(&lh[d >> 8], 1);
        }
    }
    __syncthreads();
    if (lh[tid]) gbase[tid] = atomicAdd(&bcursor[tid], lh[tid]);
    lcur[tid] = 0;
    __syncthreads();
#pragma unroll 4
    for (int j = 0; j < CHUNK / 256; j++) {
        int e = base + j * 256 + tid;
        if (e < N_EDGES) {
            int sN, d;
            if (is64) { sN = (int)e64[e]; d = (int)e64[N_EDGES + e]; }
            else      { sN = e32[e];      d = e32[N_EDGES + e]; }
            int b = d >> 8;
            int idx = gbase[b] + atomicAdd(&lcur[b], 1);
            if (idx < CAP) {    // defensive; statistically impossible to trip
                uint2 pr; pr.x = (unsigned)sN; pr.y = (unsigned)d;
                ebuck[b * CAP + idx] = pr;
            }
        }
    }
}

// per-bucket fine sort -> nodeoff(start,deg) + csr_src (block-owned region)
// 1024 threads: 4x fewer serial global-load round-trips than 256.
__global__ __launch_bounds__(BFT) void k_bfill(const uint2* __restrict__ ebuck,
        const int* __restrict__ bcursor, int2* __restrict__ nodeoff,
        int* __restrict__ csr_src) {
    __shared__ int lh[256];
    __shared__ int lexc[256];
    __shared__ int lcur[256];
    const int tid = threadIdx.x;
    const int b = blockIdx.x;
    const int lo = b * CAP;
    int cnt = bcursor[b]; if (cnt > CAP) cnt = CAP;
    const int hi = lo + cnt;
    const int n0 = b << 8;

    if (tid < 256) { lh[tid] = 0; lcur[tid] = 0; }
    __syncthreads();
    for (int i = lo + tid; i < hi; i += BFT)
        atomicAdd(&lh[ebuck[i].y & 255], 1);
    __syncthreads();
    {
        int v = 0;
        if (tid < 256) { v = lh[tid]; lexc[tid] = v; }
        __syncthreads();
        for (int o = 1; o < 256; o <<= 1) {
            int u = (tid < 256 && tid >= o) ? lexc[tid - o] : 0;
            __syncthreads();
            if (tid < 256) lexc[tid] += u;
            __syncthreads();
        }
        if (tid < 256) {
            int s = lexc[tid] - v;   // exclusive
            lexc[tid] = s;
            int node = n0 + tid;
            if (node < N_NODES) {
                int2 no; no.x = lo + s; no.y = v;
                nodeoff[node] = no;
            }
        }
    }
    __syncthreads();
    for (int i = lo + tid; i < hi; i += BFT) {
        uint2 pr = ebuck[i];
        int li = (int)(pr.y & 255);
        int p = atomicAdd(&lcur[li], 1);
        csr_src[lo + lexc[li] + p] = (int)pr.x;
    }
}

// ---------------- K3: CSR gather — 2 edges/wave, 4 ch/lane ---------------
__global__ __launch_bounds__(256) void k_gather(const int2* __restrict__ nodeoff,
        const int* __restrict__ csr_src, const float* __restrict__ a_src,
        const float* __restrict__ a_dst, const unsigned* __restrict__ h_bf,
        float* __restrict__ agg) {
    int d = blockIdx.x * 4 + (threadIdx.x >> 6);
    if (d >= N_NODES) return;
    const int lane = threadIdx.x & 63;
    const int half = lane >> 5;
    const int l32 = lane & 31;
    const int hd = l32 >> 3;             // head of channels 4*l32..+3
    int2 nd = nodeoff[d];
    const int lo = nd.x, hi = nd.x + nd.y;

    const float adh = a_dst[d * 4 + hd];

    float den = 0.f;
    float ax = 0.f, ay = 0.f, az = 0.f, aw = 0.f;

    if (half == 0) {   // self-loop on half 0
        float t = a_src[d * 4 + hd] + adh;
        t = t > 0.f ? t : 0.2f * t;
        float es = __expf(t);
        den = es;
        uint2 hu = ((const uint2*)(h_bf + (size_t)d * 64))[l32];
        float2 c01 = bf2f2(hu.x), c23 = bf2f2(hu.y);
        ax = c01.x * es; ay = c01.y * es;
        az = c23.x * es; aw = c23.y * es;
    }

    int base = lo;
    for (; base + 8 <= hi; base += 8) {
        int i0 = base + half;
        int s0 = csr_src[i0 + 0];
        int s1 = csr_src[i0 + 2];
        int s2 = csr_src[i0 + 4];
        int s3 = csr_src[i0 + 6];
        uint2 u0 = ((const uint2*)(h_bf + (size_t)s0 * 64))[l32];
        uint2 u1 = ((const uint2*)(h_bf + (size_t)s1 * 64))[l32];
        uint2 u2 = ((const uint2*)(h_bf + (size_t)s2 * 64))[l32];
        uint2 u3 = ((const uint2*)(h_bf + (size_t)s3 * 64))[l32];
        float a0 = a_src[s0 * 4 + hd];
        float a1 = a_src[s1 * 4 + hd];
        float a2 = a_src[s2 * 4 + hd];
        float a3 = a_src[s3 * 4 + hd];

        float t0 = a0 + adh; t0 = t0 > 0.f ? t0 : 0.2f * t0;
        float t1 = a1 + adh; t1 = t1 > 0.f ? t1 : 0.2f * t1;
        float t2 = a2 + adh; t2 = t2 > 0.f ? t2 : 0.2f * t2;
        float t3 = a3 + adh; t3 = t3 > 0.f ? t3 : 0.2f * t3;
        float e0 = __expf(t0);
        float e1 = __expf(t1);
        float e2 = __expf(t2);
        float e3 = __expf(t3);
        den += (e0 + e1) + (e2 + e3);

        float2 p, q;
        p = bf2f2(u0.x); q = bf2f2(u0.y);
        ax = fmaf(p.x, e0, ax); ay = fmaf(p.y, e0, ay);
        az = fmaf(q.x, e0, az); aw = fmaf(q.y, e0, aw);
        p = bf2f2(u1.x); q = bf2f2(u1.y);
        ax = fmaf(p.x, e1, ax); ay = fmaf(p.y, e1, ay);
        az = fmaf(q.x, e1, az); aw = fmaf(q.y, e1, aw);
        p = bf2f2(u2.x); q = bf2f2(u2.y);
        ax = fmaf(p.x, e2, ax); ay = fmaf(p.y, e2, ay);
        az = fmaf(q.x, e2, az); aw = fmaf(q.y, e2, aw);
        p = bf2f2(u3.x); q = bf2f2(u3.y);
        ax = fmaf(p.x, e3, ax); ay = fmaf(p.y, e3, ay);
        az = fmaf(q.x, e3, az); aw = fmaf(q.y, e3, aw);
    }
    for (int i = base + half; i < hi; i += 2) {
        int s = csr_src[i];
        float tt = a_src[s * 4 + hd] + adh;
        tt = tt > 0.f ? tt : 0.2f * tt;
        float e = __expf(tt);
        den += e;
        uint2 hu = ((const uint2*)(h_bf + (size_t)s * 64))[l32];
        float2 p = bf2f2(hu.x), q = bf2f2(hu.y);
        ax = fmaf(p.x, e, ax); ay = fmaf(p.y, e, ay);
        az = fmaf(q.x, e, az); aw = fmaf(q.y, e, aw);
    }

    // merge halves
    den += __shfl_xor(den, 32);
    ax += __shfl_xor(ax, 32);
    ay += __shfl_xor(ay, 32);
    az += __shfl_xor(az, 32);
    aw += __shfl_xor(aw, 32);

    if (half == 0) {
        float inv = 1.f / (den + 1e-16f);
        float4 o; o.x = ax * inv; o.y = ay * inv; o.z = az * inv; o.w = aw * inv;
        ((float4*)(agg + (size_t)d * 128))[l32] = o;
    }
}

// ---------------- K4: fused MLP via MFMA f16 -----------------------------
__global__ __launch_bounds__(256) void k_mlp(const float* __restrict__ agg,
        const float* __restrict__ b_gat, const _Float16* __restrict__ swz,
        const float* __restrict__ b_enc, const float* __restrict__ b_dec,
        const float* __restrict__ b_out, float* __restrict__ out) {
    __shared__ _Float16 sx[64 * 128];    // 16 KB
    __shared__ _Float16 se[4 * 16 * 64]; // 8 KB
    const int tid = threadIdx.x;
    const int m0 = blockIdx.x * 64;

#pragma unroll
    for (int i = 0; i < 8; i++) {
        int idx = tid + i * 256;
        int r = idx >> 5, c4 = idx & 31;
        int row = m0 + r; if (row >= N_NODES) row = N_NODES - 1;
        float4 v = ((const float4*)(agg + (size_t)row * 128))[c4];
        float4 bg = ((const float4*)b_gat)[c4];
        half4v h;
        h[0] = (_Float16)elu_f(v.x + bg.x);
        h[1] = (_Float16)elu_f(v.y + bg.y);
        h[2] = (_Float16)elu_f(v.z + bg.z);
        h[3] = (_Float16)elu_f(v.w + bg.w);
        *(half4v*)&sx[r * 128 + c4 * 4] = h;
    }
    __syncthreads();

    const int wave = tid >> 6, lane = tid & 63;
    const int lm = lane & 15, lq = lane >> 4;
    const int wrow = wave * 16;
    _Float16* eslab = &se[wave * 16 * 64];

    // L1: E = X1 @ W_enc + b_enc
    {
        float4v acc[4];
#pragma unroll
        for (int nt = 0; nt < 4; nt++) acc[nt] = (float4v){0.f, 0.f, 0.f, 0.f};
#pragma unroll
        for (int kc = 0; kc < 4; kc++) {
            half8 a = *(const half8*)&sx[(wrow + lm) * 128 + kc * 32 + lq * 8];
#pragma unroll
            for (int nt = 0; nt < 4; nt++) {
                half8 b = *(const half8*)&swz[(kc * 4 + nt) * 512 + lane * 8];
                acc[nt] = __builtin_amdgcn_mfma_f32_16x16x32_f16(a, b, acc[nt], 0, 0, 0);
            }
        }
#pragma unroll
        for (int nt = 0; nt < 4; nt++) {
            float be = b_enc[nt * 16 + lm];
#pragma unroll
            for (int r = 0; r < 4; r++)
                eslab[(lq * 4 + r) * 64 + nt * 16 + lm] = (_Float16)(acc[nt][r] + be);
        }
    }

    // L2: X2 = elu(E @ W_dec + b_dec) -> sx slab
    {
        float4v acc[8];
#pragma unroll
        for (int nt = 0; nt < 8; nt++) acc[nt] = (float4v){0.f, 0.f, 0.f, 0.f};
#pragma unroll
        for (int kc = 0; kc < 2; kc++) {
            half8 a = *(const half8*)&eslab[lm * 64 + kc * 32 + lq * 8];
#pragma unroll
            for (int nt = 0; nt < 8; nt++) {
                half8 b = *(const half8*)&swz[8192 + (kc * 8 + nt) * 512 + lane * 8];
                acc[nt] = __builtin_amdgcn_mfma_f32_16x16x32_f16(a, b, acc[nt], 0, 0, 0);
            }
        }
#pragma unroll
        for (int nt = 0; nt < 8; nt++) {
            float bd = b_dec[nt * 16 + lm];
#pragma unroll
            for (int r = 0; r < 4; r++)
                sx[(wrow + lq * 4 + r) * 128 + nt * 16 + lm] =
                    (_Float16)elu_f(acc[nt][r] + bd);
        }
    }

    // L3: OUT = X2 @ W_out + b_out
    {
        float4v acc[8];
#pragma unroll
        for (int nt = 0; nt < 8; nt++) acc[nt] = (float4v){0.f, 0.f, 0.f, 0.f};
#pragma unroll
        for (int kc = 0; kc < 4; kc++) {
            half8 a = *(const half8*)&sx[(wrow + lm) * 128 + kc * 32 + lq * 8];
#pragma unroll
            for (int nt = 0; nt < 8; nt++) {
                half8 b = *(const half8*)&swz[16384 + (kc * 8 + nt) * 512 + lane * 8];
                acc[nt] = __builtin_amdgcn_mfma_f32_16x16x32_f16(a, b, acc[nt], 0, 0, 0);
            }
        }
#pragma unroll
        for (int nt = 0; nt < 8; nt++) {
            float bo = b_out[nt * 16 + lm];
#pragma unroll
            for (int r = 0; r < 4; r++) {
                int row = m0 + wrow + lq * 4 + r;
                if (row < N_NODES)
                    out[(size_t)row * 128 + nt * 16 + lm] = acc[nt][r] + bo;
            }
        }
    }
}

extern "C" void kernel_launch(void* const* d_in, const int* in_sizes, int n_in,
                              void* d_out, int out_size, void* d_ws, size_t ws_size,
                              hipStream_t stream) {
    const float* x       = (const float*)d_in[0];
    const void*  e_raw   = d_in[1];
    const float* W_gat   = (const float*)d_in[2];
    const float* b_gat   = (const float*)d_in[3];
    const float* att_src = (const float*)d_in[4];
    const float* att_dst = (const float*)d_in[5];
    const float* W_enc   = (const float*)d_in[6];
    const float* b_enc   = (const float*)d_in[7];
    const float* W_dec   = (const float*)d_in[8];
    const float* b_dec   = (const float*)d_in[9];
    const float* W_out   = (const float*)d_in[10];
    const float* b_out   = (const float*)d_in[11];
    float* out = (float*)d_out;

    float* ws      = (float*)d_ws;
    float*   hreg  = ws;                       // 6,400,000 f
    unsigned* h_bf = (unsigned*)hreg;          // 3,200,000 u (50000 x 64)
    float* a_src   = hreg + 6400000;           // 200,000 f
    float* a_dst   = a_src + 200000;           // 200,000 f
    float* agg     = a_dst + 200000;           // 6,400,000 f
    uint2* ebuck   = (uint2*)agg;              // 196*CAP*8B = 9.6 MB, aliases agg
    int*   edges   = (int*)(agg + 6400000);    // (unused now, layout kept)
    int*   csr_src = edges + 1600000;          // 196*CAP = 1,204,224 i
    int2*  nodeoff = (int2*)(csr_src + NBUCK * CAP);  // 50,000 int2
    int*   flag    = (int*)(nodeoff + 50000);  // 1 i
    int*   bcursor = flag + 1;                 // 256 i
    _Float16* swz  = (_Float16*)(((uintptr_t)(bcursor + 256) + 15) & ~(uintptr_t)15); // 49152 f16

    const int GBLK = (N_NODES + BM - 1) / BM;  // 782

    k_pre<<<SWZ_BLOCKS + 1, 256, 0, stream>>>(
        e_raw, flag, W_enc, W_dec, W_out, W_gat, swz, bcursor);

    k_gat_lin<<<GBLK, 256, 0, stream>>>(x, swz, att_src, att_dst, h_bf, a_src, a_dst);

    k_bucket<<<NB_BUCKET_BLOCKS, 256, 0, stream>>>(e_raw, flag, bcursor, ebuck);
    k_bfill<<<NBUCK, BFT, 0, stream>>>(ebuck, bcursor, nodeoff, csr_src);

    k_gather<<<(N_NODES + 3) / 4, 256, 0, stream>>>(nodeoff, csr_src, a_src, a_dst, h_bf, agg);

    k_mlp<<<GBLK, 256, 0, stream>>>(agg, b_gat, swz, b_enc, b_dec, b_out, out);
}

// Round 3
// 187.352 us; speedup vs baseline: 1.1372x; 1.0361x over previous
//
#include <hip/hip_runtime.h>
#include <hip/hip_bf16.h>

#define N_NODES 50000
#define N_EDGES 800000
#define BM 64
#define NBUCK 196            // buckets of 256 nodes: d >> 8
#define CAP 8192             // per-bucket capacity (mean ~4096 real + <=1792 pad)
#define CHUNK 2048           // edges per block in bucket pass
#define NB_BUCKET_BLOCKS ((N_EDGES + CHUNK - 1) / CHUNK)   // 391
#define SWZ_BLOCKS 192                                     // 49152 halves
#define SWZ_G 32768          // W_gat offset in swz
#define BFT 1024             // k_bfill threads
#define GBLK ((N_NODES + BM - 1) / BM)                     // 782

typedef _Float16 half4v __attribute__((ext_vector_type(4)));
typedef _Float16 half8 __attribute__((ext_vector_type(8)));
typedef float    float4v __attribute__((ext_vector_type(4)));

__device__ __forceinline__ float elu_f(float v) {
    return (v > 0.f) ? v : (__expf(v) - 1.f);
}

// pack two fp32 -> packed bf16x2 (RNE)
__device__ __forceinline__ unsigned f2bf2(float a, float b) {
    unsigned ua = __float_as_uint(a), ub = __float_as_uint(b);
    ua = (ua + 0x7FFFu + ((ua >> 16) & 1u)) >> 16;
    ub = (ub + 0x7FFFu + ((ub >> 16) & 1u)) >> 16;
    return ua | (ub << 16);
}
__device__ __forceinline__ float2 bf2f2(unsigned u) {
    float2 f;
    f.x = __uint_as_float(u << 16);
    f.y = __uint_as_float(u & 0xFFFF0000u);
    return f;
}

// ---------------- pre-pass: weight swizzle + {detect, bcursor zero} ------
// swz layout: [We 0..8192) N=64 | [Wd 8192..16384) N=128 | [Wo 16384..32768)
// N=128 | [Wg 32768..49152) N=128.
__global__ __launch_bounds__(256) void k_pre(const void* __restrict__ e_raw,
        int* __restrict__ flag,
        const float* __restrict__ We, const float* __restrict__ Wd,
        const float* __restrict__ Wo, const float* __restrict__ Wg,
        _Float16* __restrict__ swz, int* __restrict__ bcursor) {
    const int b = blockIdx.x;
    const int tid = threadIdx.x;
    if (b >= SWZ_BLOCKS) {
        __shared__ int nz;
        if (tid == 0) nz = 0;
        bcursor[tid] = 0;
        __syncthreads();
        int cnt = 0;
        const unsigned* er = (const unsigned*)e_raw;
        for (int i = tid; i < 2048; i += 256)
            if (er[2 * i + 1] != 0u) cnt = 1;
        if (cnt) atomicOr(&nz, 1);
        __syncthreads();
        if (tid == 0) *flag = (nz == 0) ? 1 : 0;   // 1 == int64 layout
        return;
    }
    int t = b * 256 + tid;
    const float* W; int base, N;
    if (t < 8192)       { W = We; base = 0;     N = 64;  }
    else if (t < 16384) { W = Wd; base = 8192;  N = 128; }
    else if (t < 32768) { W = Wo; base = 16384; N = 128; }
    else                { W = Wg; base = SWZ_G; N = 128; }
    int loc = t - base;
    int nnt = N >> 4;
    int frag = loc >> 9, r = loc & 511, lane = r >> 3, j = r & 7;
    int kc = frag / nnt, nt = frag - kc * nnt;
    int k = kc * 32 + ((lane >> 4) << 3) + j;
    int n = nt * 16 + (lane & 15);
    swz[t] = (_Float16)W[k * N + n];
}

// ---------------- fused K1: bucket blocks [0,391) + gat_lin blocks -------
// Both depend only on k_pre; merging overlaps latency-bound bucket work
// with MFMA-bound gat_lin work and drops one launch.
__global__ __launch_bounds__(256) void k_gatlin_bucket(
        const float* __restrict__ x, const _Float16* __restrict__ swz,
        const float* __restrict__ att_s, const float* __restrict__ att_d,
        unsigned* __restrict__ h_bf, float* __restrict__ a_src,
        float* __restrict__ a_dst,
        const void* __restrict__ e_raw, const int* __restrict__ flag,
        int* __restrict__ bcursor, uint2* __restrict__ ebuck) {
    __shared__ __align__(16) char smem[50176];
    const int tid = threadIdx.x;

    if (blockIdx.x < NB_BUCKET_BLOCKS) {
        // ---- bucket body: single-pass fixed-cap bucket sort ----
        int* lh    = (int*)smem;
        int* gbase = (int*)(smem + 1024);
        int* lcur  = (int*)(smem + 2048);
        const int base = blockIdx.x * CHUNK;
        const int is64 = *flag;
        const long long* e64 = (const long long*)e_raw;
        const int* e32 = (const int*)e_raw;

        lh[tid] = 0;
        __syncthreads();
#pragma unroll 4
        for (int j = 0; j < CHUNK / 256; j++) {
            int e = base + j * 256 + tid;
            if (e < N_EDGES) {
                int d = is64 ? (int)e64[N_EDGES + e] : e32[N_EDGES + e];
                atomicAdd(&lh[d >> 8], 1);
            }
        }
        __syncthreads();
        if (lh[tid]) gbase[tid] = atomicAdd(&bcursor[tid], lh[tid]);
        lcur[tid] = 0;
        __syncthreads();
#pragma unroll 4
        for (int j = 0; j < CHUNK / 256; j++) {
            int e = base + j * 256 + tid;
            if (e < N_EDGES) {
                int sN, d;
                if (is64) { sN = (int)e64[e]; d = (int)e64[N_EDGES + e]; }
                else      { sN = e32[e];      d = e32[N_EDGES + e]; }
                int bb = d >> 8;
                int idx = gbase[bb] + atomicAdd(&lcur[bb], 1);
                if (idx < CAP) {
                    uint2 pr; pr.x = (unsigned)sN; pr.y = (unsigned)d;
                    ebuck[bb * CAP + idx] = pr;
                }
            }
        }
        return;
    }

    // ---- gat_lin body: h(bf16) = x @ W_gat via MFMA; att head dots ----
    _Float16* sx = (_Float16*)smem;          // 64*128 f16 = 16 KB
    float*    sh = (float*)(smem + 16384);   // 64*132 f32 = 33.8 KB (pad 132)
    const int m0 = (blockIdx.x - NB_BUCKET_BLOCKS) * 64;

#pragma unroll
    for (int i = 0; i < 8; i++) {
        int idx = tid + i * 256;        // 2048 float4 slots (64 x 32)
        int r = idx >> 5, c4 = idx & 31;
        int row = m0 + r; if (row >= N_NODES) row = N_NODES - 1;
        float4 v = ((const float4*)(x + (size_t)row * 128))[c4];
        half4v h;
        h[0] = (_Float16)v.x; h[1] = (_Float16)v.y;
        h[2] = (_Float16)v.z; h[3] = (_Float16)v.w;
        *(half4v*)&sx[r * 128 + c4 * 4] = h;
    }
    __syncthreads();

    const int wave = tid >> 6, lane = tid & 63;
    const int lm = lane & 15, lq = lane >> 4;
    const int wrow = wave * 16;

    {
        float4v acc[8];
#pragma unroll
        for (int nt = 0; nt < 8; nt++) acc[nt] = (float4v){0.f, 0.f, 0.f, 0.f};
#pragma unroll
        for (int kc = 0; kc < 4; kc++) {
            half8 a = *(const half8*)&sx[(wrow + lm) * 128 + kc * 32 + lq * 8];
#pragma unroll
            for (int nt = 0; nt < 8; nt++) {
                half8 b = *(const half8*)&swz[SWZ_G + (kc * 8 + nt) * 512 + lane * 8];
                acc[nt] = __builtin_amdgcn_mfma_f32_16x16x32_f16(a, b, acc[nt], 0, 0, 0);
            }
        }
        // C/D layout: col = nt*16 + lm, row = lq*4 + r
#pragma unroll
        for (int nt = 0; nt < 8; nt++)
#pragma unroll
            for (int r = 0; r < 4; r++)
                sh[(wrow + lq * 4 + r) * 132 + nt * 16 + lm] = acc[nt][r];
    }
    __syncthreads();

    // epilogue: pack bf16 h + attention dots (8 rows x 4 cols per thread)
    const int c0 = (tid & 31) * 4;
    const int r0 = (tid >> 5) * 8;
    float4 as4 = *(const float4*)&att_s[c0];
    float4 ad4 = *(const float4*)&att_d[c0];
    const int head = c0 >> 5;

#pragma unroll
    for (int r = 0; r < 8; r++) {
        int row = m0 + r0 + r;
        bool ok = row < N_NODES;
        float4 hv = *(const float4*)&sh[(r0 + r) * 132 + c0];
        if (ok) {
            uint2 p;
            p.x = f2bf2(hv.x, hv.y);
            p.y = f2bf2(hv.z, hv.w);
            *(uint2*)&h_bf[(size_t)row * 64 + (c0 >> 1)] = p;
        }
        float vs = hv.x * as4.x + hv.y * as4.y + hv.z * as4.z + hv.w * as4.w;
        float vd = hv.x * ad4.x + hv.y * ad4.y + hv.z * ad4.z + hv.w * ad4.w;
#pragma unroll
        for (int o = 4; o >= 1; o >>= 1) {
            vs += __shfl_down(vs, o, 8);
            vd += __shfl_down(vd, o, 8);
        }
        if (ok && (tid & 7) == 0) {
            a_src[row * 4 + head] = vs;
            a_dst[row * 4 + head] = vd;
        }
    }
}

// per-bucket fine sort -> nodeoff(start, padded_len) + csr_src.
// Per-node segments padded to multiples of 8 with sentinel -1 so the
// gather kernel runs only its 8-wide unrolled loop (no tail).
__global__ __launch_bounds__(BFT) void k_bfill(const uint2* __restrict__ ebuck,
        const int* __restrict__ bcursor, int2* __restrict__ nodeoff,
        int* __restrict__ csr_src) {
    __shared__ int lh[256];
    __shared__ int lexc[256];
    __shared__ int lcur[256];
    const int tid = threadIdx.x;
    const int b = blockIdx.x;
    const int lo = b * CAP;
    int cnt = bcursor[b]; if (cnt > CAP) cnt = CAP;
    const int hi = lo + cnt;
    const int n0 = b << 8;

    if (tid < 256) { lh[tid] = 0; lcur[tid] = 0; }
    __syncthreads();
    for (int i = lo + tid; i < hi; i += BFT)
        atomicAdd(&lh[ebuck[i].y & 255], 1);
    __syncthreads();

    int v = 0, p = 0;
    if (tid < 256) {
        v = lh[tid];
        p = (v + 7) & ~7;       // padded length
        lexc[tid] = p;
    }
    __syncthreads();
    for (int o = 1; o < 256; o <<= 1) {
        int u = (tid < 256 && tid >= o) ? lexc[tid - o] : 0;
        __syncthreads();
        if (tid < 256) lexc[tid] += u;
        __syncthreads();
    }
    if (tid < 256) {
        int s = lexc[tid] - p;   // exclusive padded start
        lexc[tid] = s;
        int node = n0 + tid;
        if (node < N_NODES) {
            int2 no;
            no.x = lo + s;
            // defensive: never let a segment extend past the bucket region
            int maxlen = CAP - s; if (maxlen < 0) maxlen = 0;
            no.y = p <= maxlen ? p : (maxlen & ~7);
            nodeoff[node] = no;
        }
    }
    __syncthreads();

    for (int i = lo + tid; i < hi; i += BFT) {
        uint2 pr = ebuck[i];
        int li = (int)(pr.y & 255);
        int pos = atomicAdd(&lcur[li], 1);
        int dst = lexc[li] + pos;
        if (dst < CAP) csr_src[lo + dst] = (int)pr.x;   // clamp: bucket-local
    }
    // sentinel pad fill (disjoint slots from the scatter above)
    if (tid < 256) {
        int base = lexc[tid];
        for (int j = v; j < p && base + j < CAP; j++) csr_src[lo + base + j] = -1;
    }
}

// ---------------- K3: CSR gather — 8 edges/wave-iter, no tail ------------
__global__ __launch_bounds__(256) void k_gather(const int2* __restrict__ nodeoff,
        const int* __restrict__ csr_src, const float* __restrict__ a_src,
        const float* __restrict__ a_dst, const unsigned* __restrict__ h_bf,
        float* __restrict__ agg) {
    int d = blockIdx.x * 4 + (threadIdx.x >> 6);
    if (d >= N_NODES) return;
    const int lane = threadIdx.x & 63;
    const int half = lane >> 5;
    const int l32 = lane & 31;
    const int hd = l32 >> 3;             // head of channels 4*l32..+3
    int2 nd = nodeoff[d];
    const int lo = nd.x, hi = nd.x + nd.y;   // nd.y is padded (multiple of 8)

    const float adh = a_dst[d * 4 + hd];

    float den = 0.f;
    float ax = 0.f, ay = 0.f, az = 0.f, aw = 0.f;

    if (half == 0) {   // self-loop on half 0
        float t = a_src[d * 4 + hd] + adh;
        t = t > 0.f ? t : 0.2f * t;
        float es = __expf(t);
        den = es;
        uint2 hu = ((const uint2*)(h_bf + (size_t)d * 64))[l32];
        float2 c01 = bf2f2(hu.x), c23 = bf2f2(hu.y);
        ax = c01.x * es; ay = c01.y * es;
        az = c23.x * es; aw = c23.y * es;
    }

    for (int base = lo; base < hi; base += 8) {
        int i0 = base + half;
        int s0 = csr_src[i0 + 0];
        int s1 = csr_src[i0 + 2];
        int s2 = csr_src[i0 + 4];
        int s3 = csr_src[i0 + 6];
        // sentinel (-1) -> read own row (cache hit), weight forced to 0
        int g0 = s0 < 0 ? d : s0;
        int g1 = s1 < 0 ? d : s1;
        int g2 = s2 < 0 ? d : s2;
        int g3 = s3 < 0 ? d : s3;
        uint2 u0 = ((const uint2*)(h_bf + (size_t)g0 * 64))[l32];
        uint2 u1 = ((const uint2*)(h_bf + (size_t)g1 * 64))[l32];
        uint2 u2 = ((const uint2*)(h_bf + (size_t)g2 * 64))[l32];
        uint2 u3 = ((const uint2*)(h_bf + (size_t)g3 * 64))[l32];
        float a0 = a_src[g0 * 4 + hd];
        float a1 = a_src[g1 * 4 + hd];
        float a2 = a_src[g2 * 4 + hd];
        float a3 = a_src[g3 * 4 + hd];

        float t0 = a0 + adh; t0 = t0 > 0.f ? t0 : 0.2f * t0;
        float t1 = a1 + adh; t1 = t1 > 0.f ? t1 : 0.2f * t1;
        float t2 = a2 + adh; t2 = t2 > 0.f ? t2 : 0.2f * t2;
        float t3 = a3 + adh; t3 = t3 > 0.f ? t3 : 0.2f * t3;
        float e0 = s0 < 0 ? 0.f : __expf(t0);
        float e1 = s1 < 0 ? 0.f : __expf(t1);
        float e2 = s2 < 0 ? 0.f : __expf(t2);
        float e3 = s3 < 0 ? 0.f : __expf(t3);
        den += (e0 + e1) + (e2 + e3);

        float2 p, q;
        p = bf2f2(u0.x); q = bf2f2(u0.y);
        ax = fmaf(p.x, e0, ax); ay = fmaf(p.y, e0, ay);
        az = fmaf(q.x, e0, az); aw = fmaf(q.y, e0, aw);
        p = bf2f2(u1.x); q = bf2f2(u1.y);
        ax = fmaf(p.x, e1, ax); ay = fmaf(p.y, e1, ay);
        az = fmaf(q.x, e1, az); aw = fmaf(q.y, e1, aw);
        p = bf2f2(u2.x); q = bf2f2(u2.y);
        ax = fmaf(p.x, e2, ax); ay = fmaf(p.y, e2, ay);
        az = fmaf(q.x, e2, az); aw = fmaf(q.y, e2, aw);
        p = bf2f2(u3.x); q = bf2f2(u3.y);
        ax = fmaf(p.x, e3, ax); ay = fmaf(p.y, e3, ay);
        az = fmaf(q.x, e3, az); aw = fmaf(q.y, e3, aw);
    }

    // merge halves
    den += __shfl_xor(den, 32);
    ax += __shfl_xor(ax, 32);
    ay += __shfl_xor(ay, 32);
    az += __shfl_xor(az, 32);
    aw += __shfl_xor(aw, 32);

    if (half == 0) {
        float inv = 1.f / (den + 1e-16f);
        float4 o; o.x = ax * inv; o.y = ay * inv; o.z = az * inv; o.w = aw * inv;
        ((float4*)(agg + (size_t)d * 128))[l32] = o;
    }
}

// ---------------- K4: fused MLP via MFMA f16 -----------------------------
__global__ __launch_bounds__(256) void k_mlp(const float* __restrict__ agg,
        const float* __restrict__ b_gat, const _Float16* __restrict__ swz,
        const float* __restrict__ b_enc, const float* __restrict__ b_dec,
        const float* __restrict__ b_out, float* __restrict__ out) {
    __shared__ _Float16 sx[64 * 128];    // 16 KB
    __shared__ _Float16 se[4 * 16 * 64]; // 8 KB
    const int tid = threadIdx.x;
    const int m0 = blockIdx.x * 64;

#pragma unroll
    for (int i = 0; i < 8; i++) {
        int idx = tid + i * 256;
        int r = idx >> 5, c4 = idx & 31;
        int row = m0 + r; if (row >= N_NODES) row = N_NODES - 1;
        float4 v = ((const float4*)(agg + (size_t)row * 128))[c4];
        float4 bg = ((const float4*)b_gat)[c4];
        half4v h;
        h[0] = (_Float16)elu_f(v.x + bg.x);
        h[1] = (_Float16)elu_f(v.y + bg.y);
        h[2] = (_Float16)elu_f(v.z + bg.z);
        h[3] = (_Float16)elu_f(v.w + bg.w);
        *(half4v*)&sx[r * 128 + c4 * 4] = h;
    }
    __syncthreads();

    const int wave = tid >> 6, lane = tid & 63;
    const int lm = lane & 15, lq = lane >> 4;
    const int wrow = wave * 16;
    _Float16* eslab = &se[wave * 16 * 64];

    // L1: E = X1 @ W_enc + b_enc
    {
        float4v acc[4];
#pragma unroll
        for (int nt = 0; nt < 4; nt++) acc[nt] = (float4v){0.f, 0.f, 0.f, 0.f};
#pragma unroll
        for (int kc = 0; kc < 4; kc++) {
            half8 a = *(const half8*)&sx[(wrow + lm) * 128 + kc * 32 + lq * 8];
#pragma unroll
            for (int nt = 0; nt < 4; nt++) {
                half8 b = *(const half8*)&swz[(kc * 4 + nt) * 512 + lane * 8];
                acc[nt] = __builtin_amdgcn_mfma_f32_16x16x32_f16(a, b, acc[nt], 0, 0, 0);
            }
        }
#pragma unroll
        for (int nt = 0; nt < 4; nt++) {
            float be = b_enc[nt * 16 + lm];
#pragma unroll
            for (int r = 0; r < 4; r++)
                eslab[(lq * 4 + r) * 64 + nt * 16 + lm] = (_Float16)(acc[nt][r] + be);
        }
    }

    // L2: X2 = elu(E @ W_dec + b_dec) -> sx slab
    {
        float4v acc[8];
#pragma unroll
        for (int nt = 0; nt < 8; nt++) acc[nt] = (float4v){0.f, 0.f, 0.f, 0.f};
#pragma unroll
        for (int kc = 0; kc < 2; kc++) {
            half8 a = *(const half8*)&eslab[lm * 64 + kc * 32 + lq * 8];
#pragma unroll
            for (int nt = 0; nt < 8; nt++) {
                half8 b = *(const half8*)&swz[8192 + (kc * 8 + nt) * 512 + lane * 8];
                acc[nt] = __builtin_amdgcn_mfma_f32_16x16x32_f16(a, b, acc[nt], 0, 0, 0);
            }
        }
#pragma unroll
        for (int nt = 0; nt < 8; nt++) {
            float bd = b_dec[nt * 16 + lm];
#pragma unroll
            for (int r = 0; r < 4; r++)
                sx[(wrow + lq * 4 + r) * 128 + nt * 16 + lm] =
                    (_Float16)elu_f(acc[nt][r] + bd);
        }
    }

    // L3: OUT = X2 @ W_out + b_out
    {
        float4v acc[8];
#pragma unroll
        for (int nt = 0; nt < 8; nt++) acc[nt] = (float4v){0.f, 0.f, 0.f, 0.f};
#pragma unroll
        for (int kc = 0; kc < 4; kc++) {
            half8 a = *(const half8*)&sx[(wrow + lm) * 128 + kc * 32 + lq * 8];
#pragma unroll
            for (int nt = 0; nt < 8; nt++) {
                half8 b = *(const half8*)&swz[16384 + (kc * 8 + nt) * 512 + lane * 8];
                acc[nt] = __builtin_amdgcn_mfma_f32_16x16x32_f16(a, b, acc[nt], 0, 0, 0);
            }
        }
#pragma unroll
        for (int nt = 0; nt < 8; nt++) {
            float bo = b_out[nt * 16 + lm];
#pragma unroll
            for (int r = 0; r < 4; r++) {
                int row = m0 + wrow + lq * 4 + r;
                if (row < N_NODES)
                    out[(size_t)row * 128 + nt * 16 + lm] = acc[nt][r] + bo;
            }
        }
    }
}

extern "C" void kernel_launch(void* const* d_in, const int* in_sizes, int n_in,
                              void* d_out, int out_size, void* d_ws, size_t ws_size,
                              hipStream_t stream) {
    const float* x       = (const float*)d_in[0];
    const void*  e_raw   = d_in[1];
    const float* W_gat   = (const float*)d_in[2];
    const float* b_gat   = (const float*)d_in[3];
    const float* att_src = (const float*)d_in[4];
    const float* att_dst = (const float*)d_in[5];
    const float* W_enc   = (const float*)d_in[6];
    const float* b_enc   = (const float*)d_in[7];
    const float* W_dec   = (const float*)d_in[8];
    const float* b_dec   = (const float*)d_in[9];
    const float* W_out   = (const float*)d_in[10];
    const float* b_out   = (const float*)d_in[11];
    float* out = (float*)d_out;

    float* ws      = (float*)d_ws;
    float*   hreg  = ws;                       // 6,400,000 f
    unsigned* h_bf = (unsigned*)hreg;          // 3,200,000 u (50000 x 64)
    float* a_src   = hreg + 6400000;           // 200,000 f
    float* a_dst   = a_src + 200000;           // 200,000 f
    float* agg     = a_dst + 200000;           // 6,400,000 f
    uint2* ebuck   = (uint2*)agg;              // 196*8192*8B = 12.85 MB, aliases agg
    int*   csr_src = (int*)(agg + 6400000);    // 196*8192 = 1,605,632 i
    int2*  nodeoff = (int2*)(csr_src + NBUCK * CAP);  // 50,000 int2
    int*   flag    = (int*)(nodeoff + 50000);  // 1 i
    int*   bcursor = flag + 1;                 // 256 i
    _Float16* swz  = (_Float16*)(((uintptr_t)(bcursor + 256) + 15) & ~(uintptr_t)15); // 49152 f16

    k_pre<<<SWZ_BLOCKS + 1, 256, 0, stream>>>(
        e_raw, flag, W_enc, W_dec, W_out, W_gat, swz, bcursor);

    k_gatlin_bucket<<<NB_BUCKET_BLOCKS + GBLK, 256, 0, stream>>>(
        x, swz, att_src, att_dst, h_bf, a_src, a_dst,
        e_raw, flag, bcursor, ebuck);

    k_bfill<<<NBUCK, BFT, 0, stream>>>(ebuck, bcursor, nodeoff, csr_src);

    k_gather<<<(N_NODES + 3) / 4, 256, 0, stream>>>(nodeoff, csr_src, a_src, a_dst, h_bf, agg);

    k_mlp<<<GBLK, 256, 0, stream>>>(agg, b_gat, swz, b_enc, b_dec, b_out, out);
}